// Round 1
// baseline (83.730 us; speedup 1.0000x reference)
//
#include <hip/hip_runtime.h>

// GAT layer, B=8, N=1024, INP=7, hidden=64, D=32, H=4.
// Algebra: softmax_j(s_i + s_j + ba) == softmax_j(s_j) (shift-invariance), so
// attention weights and G[b,h,:] = sum_j p[j,h] fx[j,:] are i-independent;
// every output row of batch b equals (concat_h G[b,h,:]/Z[b,h]) @ Ws + bs.
//
// R6: weights/biases/x read DIRECTLY from global (L1-resident broadcast: all
// blocks share the same 26 KB of W) instead of LDS-staged -- removes the
// staging phase and moves weight reads off the LDS pipe (layer2 was
// LDS-issue-bound at ~3072 ds-cyc/block). TR 32->16, 512 blocks x 128 thr
// = 2 blocks/CU so barrier/phase latency of one block overlaps the other's
// compute (R5 had 1 block/CU, fully exposed latency). LDS now only holds
// h1/h2/fx/e (~11.3 KB/block).

#define BB 8
#define NN 1024
#define TR 16            // rows per k1 block
#define NB1 512          // k1 blocks = 8192/TR
#define NPB 64           // k1 partial blocks per batch = NB1/8

// ---------------------------------------------------------------------------
// k1: 512 blocks x 128 threads. MLP for a 16-row tile + e=exp(s_j) + partial
// G (4x32) and Z (4) written to ws[blk].
// ---------------------------------------------------------------------------
__global__ __launch_bounds__(128) void gat_k1(
    const float* __restrict__ x,
    const float* __restrict__ W1, const float* __restrict__ b1,
    const float* __restrict__ W2, const float* __restrict__ b2,
    const float* __restrict__ W3, const float* __restrict__ b3,
    const float* __restrict__ Wa,
    float* __restrict__ Gp, float* __restrict__ Zp)
{
    const int t   = threadIdx.x;
    const int blk = blockIdx.x;

    __shared__ float h1s[TR * 68];    // stride 68 (pad keeps 16B align, no 4-way+)
    __shared__ float h2s[TR * 68];
    __shared__ float fxs[TR * 36];    // stride 36
    __shared__ float es[TR * 4];      // e[r][h]

    // ---- layer 1: [7]->[64], lrelu. 128 thr: 1 row x 8 cols ----
    {
        const int r   = t >> 3;            // 0..15
        const int o0  = (t & 7) * 8;       // 0..56
        const int row = blk * TR + r;
        float xv[7];
#pragma unroll
        for (int k = 0; k < 7; ++k) xv[k] = x[row * 7 + k];
        const float4 ba4 = *(const float4*)&b1[o0];
        const float4 bb4 = *(const float4*)&b1[o0 + 4];
        float acc[8] = {ba4.x, ba4.y, ba4.z, ba4.w, bb4.x, bb4.y, bb4.z, bb4.w};
#pragma unroll
        for (int k = 0; k < 7; ++k) {
            const float4 wa = *(const float4*)&W1[k * 64 + o0];
            const float4 wb = *(const float4*)&W1[k * 64 + o0 + 4];
            acc[0] = fmaf(xv[k], wa.x, acc[0]);
            acc[1] = fmaf(xv[k], wa.y, acc[1]);
            acc[2] = fmaf(xv[k], wa.z, acc[2]);
            acc[3] = fmaf(xv[k], wa.w, acc[3]);
            acc[4] = fmaf(xv[k], wb.x, acc[4]);
            acc[5] = fmaf(xv[k], wb.y, acc[5]);
            acc[6] = fmaf(xv[k], wb.z, acc[6]);
            acc[7] = fmaf(xv[k], wb.w, acc[7]);
        }
#pragma unroll
        for (int j = 0; j < 8; ++j) acc[j] = fmaxf(acc[j], 0.2f * acc[j]);
        *(float4*)&h1s[r * 68 + o0]     = make_float4(acc[0], acc[1], acc[2], acc[3]);
        *(float4*)&h1s[r * 68 + o0 + 4] = make_float4(acc[4], acc[5], acc[6], acc[7]);
    }
    __syncthreads();

    // ---- layer 2: [64]->[64], lrelu. 128 thr: 2 rows x 4 cols ----
    // h rows from LDS (2 ds_read_b128 / k4), W2 rows from global (L1 broadcast)
    {
        const int r0 = (t >> 4) * 2;       // 0,2,..,14
        const int o0 = (t & 15) * 4;       // 0..60
        const float4 b4 = *(const float4*)&b2[o0];
        float a0[4] = {b4.x, b4.y, b4.z, b4.w};
        float a1[4] = {b4.x, b4.y, b4.z, b4.w};
#pragma unroll
        for (int k4 = 0; k4 < 64; k4 += 4) {
            const float4 h0 = *(const float4*)&h1s[r0 * 68 + k4];
            const float4 h1 = *(const float4*)&h1s[(r0 + 1) * 68 + k4];
            const float h0v[4] = {h0.x, h0.y, h0.z, h0.w};
            const float h1v[4] = {h1.x, h1.y, h1.z, h1.w};
#pragma unroll
            for (int kk = 0; kk < 4; ++kk) {
                const float4 w = *(const float4*)&W2[(k4 + kk) * 64 + o0];
                a0[0] = fmaf(h0v[kk], w.x, a0[0]);
                a0[1] = fmaf(h0v[kk], w.y, a0[1]);
                a0[2] = fmaf(h0v[kk], w.z, a0[2]);
                a0[3] = fmaf(h0v[kk], w.w, a0[3]);
                a1[0] = fmaf(h1v[kk], w.x, a1[0]);
                a1[1] = fmaf(h1v[kk], w.y, a1[1]);
                a1[2] = fmaf(h1v[kk], w.z, a1[2]);
                a1[3] = fmaf(h1v[kk], w.w, a1[3]);
            }
        }
#pragma unroll
        for (int j = 0; j < 4; ++j) {
            a0[j] = fmaxf(a0[j], 0.2f * a0[j]);
            a1[j] = fmaxf(a1[j], 0.2f * a1[j]);
        }
        *(float4*)&h2s[r0 * 68 + o0]       = make_float4(a0[0], a0[1], a0[2], a0[3]);
        *(float4*)&h2s[(r0 + 1) * 68 + o0] = make_float4(a1[0], a1[1], a1[2], a1[3]);
    }
    __syncthreads();

    // ---- layer 3: [64]->[32]. 128 thr: 1 row x 4 cols ----
    {
        const int r  = t >> 3;             // 0..15
        const int o0 = (t & 7) * 4;        // 0..28
        const float4 b4 = *(const float4*)&b3[o0];
        float a[4] = {b4.x, b4.y, b4.z, b4.w};
#pragma unroll
        for (int k4 = 0; k4 < 64; k4 += 4) {
            const float4 h = *(const float4*)&h2s[r * 68 + k4];
            const float hv[4] = {h.x, h.y, h.z, h.w};
#pragma unroll
            for (int kk = 0; kk < 4; ++kk) {
                const float4 w = *(const float4*)&W3[(k4 + kk) * 32 + o0];
                a[0] = fmaf(hv[kk], w.x, a[0]);
                a[1] = fmaf(hv[kk], w.y, a[1]);
                a[2] = fmaf(hv[kk], w.z, a[2]);
                a[3] = fmaf(hv[kk], w.w, a[3]);
            }
        }
        *(float4*)&fxs[r * 36 + o0] = make_float4(a[0], a[1], a[2], a[3]);
    }
    __syncthreads();

    // ---- e[r][h] = exp(fx[r,:] . Wa2[:,h])  (no max-sub: s_j is O(1)) ----
    if (t < TR * 4) {
        const int r = t >> 2, h = t & 3;
        float s = 0.f;
#pragma unroll
        for (int k4 = 0; k4 < 32; k4 += 4) {
            const float4 f = *(const float4*)&fxs[r * 36 + k4];
            s = fmaf(f.x, Wa[128 + (k4 + 0) * 4 + h], s);   // Wa rows 32..63
            s = fmaf(f.y, Wa[128 + (k4 + 1) * 4 + h], s);
            s = fmaf(f.z, Wa[128 + (k4 + 2) * 4 + h], s);
            s = fmaf(f.w, Wa[128 + (k4 + 3) * 4 + h], s);
        }
        es[r * 4 + h] = __expf(s);
    }
    __syncthreads();

    // ---- block partials: G[h][d] (128 threads), Z[h] (4 threads) ----
    {
        const int h = t >> 5, d = t & 31;
        float g = 0.f;
#pragma unroll
        for (int r = 0; r < TR; ++r) g = fmaf(es[r * 4 + h], fxs[r * 36 + d], g);
        Gp[blk * 128 + t] = g;
    }
    if (t < 4) {
        float z = 0.f;
#pragma unroll
        for (int r = 0; r < TR; ++r) z += es[r * 4 + t];
        Zp[blk * 4 + t] = z;
    }
}

// ---------------------------------------------------------------------------
// k2: 128 blocks x 256 threads (16 slices/batch). Reduce 64 partials,
// normalize, project through Ws, broadcast 64 rows.
// ---------------------------------------------------------------------------
__global__ __launch_bounds__(256) void gat_k2(
    const float* __restrict__ Gp, const float* __restrict__ Zp,
    const float* __restrict__ Ws, const float* __restrict__ bs,
    float* __restrict__ out)
{
    const int blk   = blockIdx.x;
    const int b     = blk >> 4;
    const int slice = blk & 15;
    const int t     = threadIdx.x;

    __shared__ float Gc[128];
    __shared__ float zsh[4];
    __shared__ float red[8 * 32];
    __shared__ float orow[32];

    float g = 0.f;
    if (t < 128) {
        const float* gp = Gp + (size_t)(b * NPB) * 128 + t;
#pragma unroll 8
        for (int i = 0; i < NPB; ++i) g += gp[i * 128];
    } else if (t < 132) {
        const int h = t - 128;
        float z = 0.f;
#pragma unroll 8
        for (int i = 0; i < NPB; ++i) z += Zp[(b * NPB + i) * 4 + h];
        zsh[h] = z;
    }
    __syncthreads();
    if (t < 128) Gc[t] = g / zsh[t >> 5];
    __syncthreads();

    // orow[o] = bs[o] + sum_k Gc[k] * Ws[k*32+o]; k split over 8 groups
    {
        const int o = t & 31, p = t >> 5;
        float a = (p == 0) ? bs[o] : 0.f;
#pragma unroll
        for (int kk = 0; kk < 16; ++kk) {
            const int k = p * 16 + kk;
            a = fmaf(Gc[k], Ws[k * 32 + o], a);
        }
        red[p * 32 + o] = a;
    }
    __syncthreads();
    if (t < 32) {
        float a = 0.f;
#pragma unroll
        for (int p = 0; p < 8; ++p) a += red[p * 32 + t];
        orow[t] = a;
    }
    __syncthreads();

    // broadcast to 64 rows (2 per thread), fully-linear float4 stores
    const float4 v4 = ((const float4*)orow)[t & 7];
    const int rl = t >> 3;                 // 0..31
    const int row0 = slice * 64 + rl;
    ((float4*)out)[((size_t)b * NN + row0) * 8 + (t & 7)] = v4;
    ((float4*)out)[((size_t)b * NN + row0 + 32) * 8 + (t & 7)] = v4;
}

extern "C" void kernel_launch(void* const* d_in, const int* in_sizes, int n_in,
                              void* d_out, int out_size, void* d_ws, size_t ws_size,
                              hipStream_t stream) {
    const float* x  = (const float*)d_in[0];
    const float* W1 = (const float*)d_in[1];
    const float* b1 = (const float*)d_in[2];
    const float* W2 = (const float*)d_in[3];
    const float* b2 = (const float*)d_in[4];
    const float* W3 = (const float*)d_in[5];
    const float* b3 = (const float*)d_in[6];
    const float* Wa = (const float*)d_in[7];
    // d_in[8] = ba: cancels in softmax, unused
    const float* Ws = (const float*)d_in[9];
    const float* bs = (const float*)d_in[10];
    float* out = (float*)d_out;

    float* Gp = (float*)d_ws;                 // [512][128]
    float* Zp = Gp + NB1 * 128;               // [512][4]

    gat_k1<<<dim3(NB1), dim3(128), 0, stream>>>(
        x, W1, b1, W2, b2, W3, b3, Wa, Gp, Zp);
    gat_k2<<<dim3(128), dim3(256), 0, stream>>>(Gp, Zp, Ws, bs, out);
}